// Round 4
// baseline (463.938 us; speedup 1.0000x reference)
//
#include <hip/hip_runtime.h>

// Inverse 2D DWT, single level, fused column+row synthesis. FP32 throughout.
// One wave per 4-row strip, rolling 3-row register window, horizontal halos
// via cross-lane shuffle of the vertical-synthesis results.
// Round-3 lesson: per-wave MLP (prefetch) is neutral -- waves sit in vmcnt
// queues because the chip-level memory throughput for this pattern caps at
// ~3 TB/s. This round: 2x block oversubscription (16 blocks/CU) for resident
// parallelism + tail balance, and an XCD-bijective swizzle grouping all
// strips of one image on one XCD so halo rows are same-XCD L2 hits.
// out[2i+py][2j+px] = sum_{dy,dx in {-1,0,1}}
//   wh[py][dy]*wh[px][dx]*ss + wg[py][dy]*wh[px][dx]*sd
// + wh[py][dy]*wg[px][dx]*ds + wg[py][dy]*wg[px][dx]*dd
// with wh[0] = (h4,h2,h0), wh[1] = (h5,h3,h1) over dy=(-1,0,+1); reflect pad 1.

typedef float float4v __attribute__((ext_vector_type(4)));

constexpr int Hc = 256;
constexpr int Wc = 256;
constexpr int ROWS = 4;   // rows per wave strip
constexpr int WPB  = 4;   // waves per block
constexpr int GX   = Hc / (ROWS * WPB);  // 16 strips-of-blocks per image
constexpr int NXCD = 8;

__global__ __launch_bounds__(256) void idwt_kernel(
    const float* __restrict__ ss, const float* __restrict__ sd,
    const float* __restrict__ ds, const float* __restrict__ dd,
    const float* __restrict__ hf, const float* __restrict__ gf,
    float* __restrict__ out)
{
    const int lane = threadIdx.x;                     // 0..63
    const int wid  = threadIdx.y;                     // 0..WPB-1

    // XCD-bijective swizzle: nwg = GX*BC divisible by 8. Blocks with the same
    // (orig % 8) land on one XCD; give them a CONTIGUOUS chunk of logical
    // work so all strips of an image (and their shared halo rows) stay on
    // one XCD's L2.
    const int nwg  = gridDim.x * gridDim.y;
    const int orig = blockIdx.y * gridDim.x + blockIdx.x;
    const int swz  = (orig % NXCD) * (nwg / NXCD) + orig / NXCD;
    const int sx   = swz % GX;                        // strip-block within image
    const int bc   = swz / GX;                        // image index

    const int i0 = (sx * WPB + wid) * ROWS;           // first row of this strip

    const float h0 = hf[0], h1 = hf[1], h2 = hf[2];
    const float h3 = hf[3], h4 = hf[4], h5 = hf[5];
    const float g0 = gf[0], g1 = gf[1], g2 = gf[2];
    const float g3 = gf[3], g4 = gf[4], g5 = gf[5];

    const size_t off = (size_t)bc * (Hc * Wc);
    const int j0 = lane * 4;
    const float* pss = ss + off + j0;
    const float* psd = sd + off + j0;
    const float* pds = ds + off + j0;
    const float* pdd = dd + off + j0;

    auto ld = [&](const float* p, int r) -> float4v {
        return *reinterpret_cast<const float4v*>(p + (size_t)r * Wc);
    };

    // rolling 3-row windows: *_m = row i-1, *_c = row i, *_p = row i+1
    const int rm = (i0 == 0) ? 1 : i0 - 1;  // reflect-1 at top
    float4v s_m = ld(pss, rm), s_c = ld(pss, i0);
    float4v t_m = ld(psd, rm), t_c = ld(psd, i0);
    float4v u_m = ld(pds, rm), u_c = ld(pds, i0);
    float4v v_m = ld(pdd, rm), v_c = ld(pdd, i0);

    const int W2 = 2 * Wc;
    float* obase = out + (size_t)bc * (2 * Hc) * W2 + 8 * lane;

    // horizontal reflect at image edges:
    //   col -1 -> col 1 (lane 0: w[1]); col Wc -> col Wc-2 (lane 63: w[2])
    auto left = [&](const float4v& w) -> float {
        float l = __shfl_up(w[3], 1);
        return (lane == 0) ? w[1] : l;
    };
    auto right = [&](const float4v& w) -> float {
        float rr = __shfl_down(w[0], 1);
        return (lane == 63) ? w[2] : rr;
    };

    #pragma unroll
    for (int r = 0; r < ROWS; ++r) {
        const int i  = i0 + r;
        const int rn = (i + 1 < Hc) ? i + 1 : Hc - 2;  // reflect-1 at bottom
        const float4v s_p = ld(pss, rn);
        const float4v t_p = ld(psd, rn);
        const float4v u_p = ld(pds, rn);
        const float4v v_p = ld(pdd, rn);

        // vertical (column) synthesis for this wave's 4 columns
        float4v vs0, vs1, vd0, vd1;
        #pragma unroll
        for (int k = 0; k < 4; ++k) {
            vs0[k] = h4*s_m[k] + h2*s_c[k] + h0*s_p[k] + g4*t_m[k] + g2*t_c[k] + g0*t_p[k];
            vs1[k] = h5*s_m[k] + h3*s_c[k] + h1*s_p[k] + g5*t_m[k] + g3*t_c[k] + g1*t_p[k];
            vd0[k] = h4*u_m[k] + h2*u_c[k] + h0*u_p[k] + g4*v_m[k] + g2*v_c[k] + g0*v_p[k];
            vd1[k] = h5*u_m[k] + h3*u_c[k] + h1*u_p[k] + g5*v_m[k] + g3*v_c[k] + g1*v_p[k];
        }

        // 6-wide horizontal windows via shuffle (static indices only)
        const float a [6] = { left(vs0), vs0[0], vs0[1], vs0[2], vs0[3], right(vs0) };
        const float b [6] = { left(vd0), vd0[0], vd0[1], vd0[2], vd0[3], right(vd0) };
        const float c2[6] = { left(vs1), vs1[0], vs1[1], vs1[2], vs1[3], right(vs1) };
        const float d2[6] = { left(vd1), vd1[0], vd1[1], vd1[2], vd1[3], right(vd1) };

        // horizontal (row) synthesis: 2 output rows x 8 output cols
        float4v o00, o01, o10, o11;
        #pragma unroll
        for (int t = 0; t < 4; ++t) {
            const float e0 = h4*a [t] + h2*a [t+1] + h0*a [t+2] + g4*b [t] + g2*b [t+1] + g0*b [t+2];
            const float e1 = h5*a [t] + h3*a [t+1] + h1*a [t+2] + g5*b [t] + g3*b [t+1] + g1*b [t+2];
            const float f0 = h4*c2[t] + h2*c2[t+1] + h0*c2[t+2] + g4*d2[t] + g2*d2[t+1] + g0*d2[t+2];
            const float f1 = h5*c2[t] + h3*c2[t+1] + h1*c2[t+2] + g5*d2[t] + g3*d2[t+1] + g1*d2[t+2];
            if (t < 2) {
                o00[2*t]     = e0; o00[2*t+1]     = e1;
                o10[2*t]     = f0; o10[2*t+1]     = f1;
            } else {
                o01[2*(t-2)] = e0; o01[2*(t-2)+1] = e1;
                o11[2*(t-2)] = f0; o11[2*(t-2)+1] = f1;
            }
        }

        float* orow0 = obase + (size_t)(2 * i) * W2;
        float* orow1 = orow0 + W2;
        *reinterpret_cast<float4v*>(orow0)     = o00;
        *reinterpret_cast<float4v*>(orow0 + 4) = o01;
        *reinterpret_cast<float4v*>(orow1)     = o10;
        *reinterpret_cast<float4v*>(orow1 + 4) = o11;

        // shift rolling windows (register renaming under full unroll)
        s_m = s_c; s_c = s_p;
        t_m = t_c; t_c = t_p;
        u_m = u_c; u_c = u_p;
        v_m = v_c; v_c = v_p;
    }
}

extern "C" void kernel_launch(void* const* d_in, const int* in_sizes, int n_in,
                              void* d_out, int out_size, void* d_ws, size_t ws_size,
                              hipStream_t stream) {
    const float* ss = (const float*)d_in[0];
    const float* sd = (const float*)d_in[1];
    const float* ds = (const float*)d_in[2];
    const float* dd = (const float*)d_in[3];
    const float* hf = (const float*)d_in[4];
    const float* gf = (const float*)d_in[5];
    float* out = (float*)d_out;

    const int BC = in_sizes[0] / (Hc * Wc);   // B*C = 256
    dim3 block(64, WPB);                       // 1 wave x 4 strips per block
    dim3 grid(GX, BC);                         // (16, 256) = 4096 blocks
    idwt_kernel<<<grid, block, 0, stream>>>(ss, sd, ds, dd, hf, gf, out);
}

// Round 5
// 450.691 us; speedup vs baseline: 1.0294x; 1.0294x over previous
//
#include <hip/hip_runtime.h>

// Inverse 2D DWT, single level, fused column+row synthesis. FP32 throughout.
// Round-4 lesson: parallelism knobs (prefetch, oversubscription, swizzle) are
// all neutral -- the limiter is transaction efficiency. Old layout stored each
// output row as two dwordx4 instructions at 32B lane stride = HALF-LINE writes
// per instruction (R2's NT-store +18% HBM write amplification is the
// fingerprint). This version: each lane owns 2 input cols (dwordx2 loads), so
// its 4 output cols per row are one contiguous 16B chunk -> each store
// instruction writes a contiguous 1KB span with every 64B line fully covered.
// Wave covers a 128-col half-width tile; seam halo (col 127/128) via a uniform
// scalar load + redundant seam vertical synthesis; image-edge reflects are
// lane-local.
// out[2i+py][2j+px] = sum_{dy,dx in {-1,0,1}}
//   wh[py][dy]*wh[px][dx]*ss + wg[py][dy]*wh[px][dx]*sd
// + wh[py][dy]*wg[px][dx]*ds + wg[py][dy]*wg[px][dx]*dd
// with wh[0] = (h4,h2,h0), wh[1] = (h5,h3,h1) over dy=(-1,0,+1); reflect pad 1.

typedef float float2v __attribute__((ext_vector_type(2)));
typedef float float4v __attribute__((ext_vector_type(4)));

constexpr int Hc = 256;
constexpr int Wc = 256;
constexpr int ROWS = 8;   // rows per wave strip
constexpr int TW   = 128; // input cols per wave tile (2 tiles per image)

__global__ __launch_bounds__(256) void idwt_kernel(
    const float* __restrict__ ss, const float* __restrict__ sd,
    const float* __restrict__ ds, const float* __restrict__ dd,
    const float* __restrict__ hf, const float* __restrict__ gf,
    float* __restrict__ out)
{
    const int lane = threadIdx.x;        // 0..63
    const int wv   = threadIdx.y;        // 0..3
    const int tile = wv & 1;             // 0 = cols [0,128), 1 = cols [128,256)
    const int rs   = wv >> 1;            // row-strip within block (0..1)
    const int i0   = (blockIdx.x * 2 + rs) * ROWS;
    const int bc   = blockIdx.y;         // 0..B*C-1

    const float h0 = hf[0], h1 = hf[1], h2 = hf[2];
    const float h3 = hf[3], h4 = hf[4], h5 = hf[5];
    const float g0 = gf[0], g1 = gf[1], g2 = gf[2];
    const float g3 = gf[3], g4 = gf[4], g5 = gf[5];

    const size_t off = (size_t)bc * (Hc * Wc);
    const int c0 = tile * TW + 2 * lane;       // this lane's first input col
    const float* pss = ss + off;
    const float* psd = sd + off;
    const float* pds = ds + off;
    const float* pdd = dd + off;

    auto ld2 = [&](const float* p, int r) -> float2v {
        return *reinterpret_cast<const float2v*>(p + (size_t)r * Wc + c0);
    };
    // seam column: left tile needs col 128 (right neighbor of col 127),
    // right tile needs col 127 (left neighbor of col 128). Uniform address
    // across the wave -> one hot line, broadcast.
    const int seam = tile ? (TW - 1) : TW;
    auto lde = [&](const float* p, int r) -> float {
        return p[(size_t)r * Wc + seam];
    };

    // rolling 3-row windows: *_m = row i-1, *_c = row i (+ seam scalars e*)
    const int rm = (i0 == 0) ? 1 : i0 - 1;  // reflect-1 at top
    float2v s_m = ld2(pss, rm), s_c = ld2(pss, i0);
    float2v t_m = ld2(psd, rm), t_c = ld2(psd, i0);
    float2v u_m = ld2(pds, rm), u_c = ld2(pds, i0);
    float2v v_m = ld2(pdd, rm), v_c = ld2(pdd, i0);
    float es_m = lde(pss, rm), es_c = lde(pss, i0);
    float et_m = lde(psd, rm), et_c = lde(psd, i0);
    float eu_m = lde(pds, rm), eu_c = lde(pds, i0);
    float ev_m = lde(pdd, rm), ev_c = lde(pdd, i0);

    const int W2 = 2 * Wc;
    float* obase = out + (size_t)bc * (2 * Hc) * W2 + tile * (2 * TW) + 4 * lane;

    #pragma unroll
    for (int r = 0; r < ROWS; ++r) {
        const int i  = i0 + r;
        const int rn = (i + 1 < Hc) ? i + 1 : Hc - 2;  // reflect-1 at bottom
        const float2v s_p = ld2(pss, rn);
        const float2v t_p = ld2(psd, rn);
        const float2v u_p = ld2(pds, rn);
        const float2v v_p = ld2(pdd, rn);
        const float es_p = lde(pss, rn);
        const float et_p = lde(psd, rn);
        const float eu_p = lde(pds, rn);
        const float ev_p = lde(pdd, rn);

        // vertical (column) synthesis for this lane's 2 columns
        float2v vs0, vs1, vd0, vd1;
        #pragma unroll
        for (int k = 0; k < 2; ++k) {
            vs0[k] = h4*s_m[k] + h2*s_c[k] + h0*s_p[k] + g4*t_m[k] + g2*t_c[k] + g0*t_p[k];
            vs1[k] = h5*s_m[k] + h3*s_c[k] + h1*s_p[k] + g5*t_m[k] + g3*t_c[k] + g1*t_p[k];
            vd0[k] = h4*u_m[k] + h2*u_c[k] + h0*u_p[k] + g4*v_m[k] + g2*v_c[k] + g0*v_p[k];
            vd1[k] = h5*u_m[k] + h3*u_c[k] + h1*u_p[k] + g5*v_m[k] + g3*v_c[k] + g1*v_p[k];
        }
        // seam column vertical synthesis (redundant across lanes, 24 FMA)
        const float sS0 = h4*es_m + h2*es_c + h0*es_p + g4*et_m + g2*et_c + g0*et_p;
        const float sS1 = h5*es_m + h3*es_c + h1*es_p + g5*et_m + g3*et_c + g1*et_p;
        const float sD0 = h4*eu_m + h2*eu_c + h0*eu_p + g4*ev_m + g2*ev_c + g0*ev_p;
        const float sD1 = h5*eu_m + h3*eu_c + h1*eu_p + g5*ev_m + g3*ev_c + g1*ev_p;

        // horizontal neighbors: interior via shuffle; lane 0 / lane 63 take
        // image-edge reflect (lane-local) or the seam value.
        auto lnb = [&](const float2v& v, float sv) -> float {
            float x = __shfl_up(v[1], 1);
            return (lane == 0) ? (tile ? sv : v[1]) : x;   // col -1 -> col 1
        };
        auto rnb = [&](const float2v& v, float sv) -> float {
            float x = __shfl_down(v[0], 1);
            return (lane == 63) ? (tile ? v[0] : sv) : x;  // col 256 -> col 254
        };
        const float La = lnb(vs0, sS0), Ra = rnb(vs0, sS0);
        const float Lb = lnb(vd0, sD0), Rb = rnb(vd0, sD0);
        const float Lc = lnb(vs1, sS1), Rc = rnb(vs1, sS1);
        const float Ld = lnb(vd1, sD1), Rd = rnb(vd1, sD1);

        // horizontal (row) synthesis: lane's 4 contiguous output cols x 2 rows
        float4v o0, o1;
        o0[0] = h4*La      + h2*vs0[0] + h0*vs0[1] + g4*Lb      + g2*vd0[0] + g0*vd0[1];
        o0[1] = h5*La      + h3*vs0[0] + h1*vs0[1] + g5*Lb      + g3*vd0[0] + g1*vd0[1];
        o0[2] = h4*vs0[0]  + h2*vs0[1] + h0*Ra     + g4*vd0[0]  + g2*vd0[1] + g0*Rb;
        o0[3] = h5*vs0[0]  + h3*vs0[1] + h1*Ra     + g5*vd0[0]  + g3*vd0[1] + g1*Rb;
        o1[0] = h4*Lc      + h2*vs1[0] + h0*vs1[1] + g4*Ld      + g2*vd1[0] + g0*vd1[1];
        o1[1] = h5*Lc      + h3*vs1[0] + h1*vs1[1] + g5*Ld      + g3*vd1[0] + g1*vd1[1];
        o1[2] = h4*vs1[0]  + h2*vs1[1] + h0*Rc     + g4*vd1[0]  + g2*vd1[1] + g0*Rd;
        o1[3] = h5*vs1[0]  + h3*vs1[1] + h1*Rc     + g5*vd1[0]  + g3*vd1[1] + g1*Rd;

        // full-line stores: one dwordx4 per output row, lane stride 16B ->
        // contiguous 1KB span, every 64B line fully written by one instruction
        float* orow0 = obase + (size_t)(2 * i) * W2;
        *reinterpret_cast<float4v*>(orow0)      = o0;
        *reinterpret_cast<float4v*>(orow0 + W2) = o1;

        // shift rolling windows
        s_m = s_c; s_c = s_p;  t_m = t_c; t_c = t_p;
        u_m = u_c; u_c = u_p;  v_m = v_c; v_c = v_p;
        es_m = es_c; es_c = es_p;  et_m = et_c; et_c = et_p;
        eu_m = eu_c; eu_c = eu_p;  ev_m = ev_c; ev_c = ev_p;
    }
}

extern "C" void kernel_launch(void* const* d_in, const int* in_sizes, int n_in,
                              void* d_out, int out_size, void* d_ws, size_t ws_size,
                              hipStream_t stream) {
    const float* ss = (const float*)d_in[0];
    const float* sd = (const float*)d_in[1];
    const float* ds = (const float*)d_in[2];
    const float* dd = (const float*)d_in[3];
    const float* hf = (const float*)d_in[4];
    const float* gf = (const float*)d_in[5];
    float* out = (float*)d_out;

    const int BC = in_sizes[0] / (Hc * Wc);   // B*C = 256
    dim3 block(64, 4);                         // waves: 2 tiles x 2 row-strips
    dim3 grid(Hc / (ROWS * 2), BC);            // (16, 256)
    idwt_kernel<<<grid, block, 0, stream>>>(ss, sd, ds, dd, hf, gf, out);
}